// Round 3
// baseline (401.162 us; speedup 1.0000x reference)
//
#include <hip/hip_runtime.h>
#include <math.h>

#define N_PED 768
#define NW 12  // 768/64 u64 words per adjacency row (24 u32)

// ---------------- ws layout (bytes) ----------------
// A      : [16][768] double   @ 0        (98304)
// P      : [33] double        @ 98304    (264)  -> w2eff[16], b1[16], c0
// adjw   : [768*12] u64       @ 98568    (73728)
// idx    : [768] int          @ 172296   (3072)
// pool   : [16][768] float    @ 175368   (49152)

// K1: per-pedestrian features -> A[o][n] = sum_k g1_w[o,k]*F[n,k]  (f64)
__global__ __launch_bounds__(256) void k1_prep(
    const float* __restrict__ va, const float* __restrict__ vr,
    const float* __restrict__ velw, const float* __restrict__ velb,
    const float* __restrict__ g1w, const float* __restrict__ g1b,
    const float* __restrict__ gam, const float* __restrict__ bet,
    const float* __restrict__ g2w, const float* __restrict__ g2b,
    double* __restrict__ A, double* __restrict__ P) {
  int n = blockIdx.x * 256 + threadIdx.x;
  if (n >= N_PED) return;
  double F[32];
#pragma unroll
  for (int c = 0; c < 2; ++c)
#pragma unroll
    for (int t = 0; t < 8; ++t)
      F[c * 8 + t] = (double)va[(c * 8 + t) * N_PED + n];
#pragma unroll
  for (int o = 0; o < 2; ++o)
#pragma unroll
    for (int t = 0; t < 8; ++t)
      F[(2 + o) * 8 + t] = (double)velb[o]
          + (double)velw[o * 2 + 0] * (double)vr[(0 + t) * N_PED + n]
          + (double)velw[o * 2 + 1] * (double)vr[(8 + t) * N_PED + n];
  for (int o = 0; o < 16; ++o) {
    double s = 0.0;
#pragma unroll
    for (int k = 0; k < 32; ++k) s += (double)g1w[o * 32 + k] * F[k];
    A[o * N_PED + n] = s;
  }
  if (n < 16) {
    const double inv_std = 1.0 / sqrt(1.0 + 1e-5);
    P[n] = (double)g2w[n] * inv_std * (double)gam[n];  // w2eff
    P[16 + n] = (double)g1b[n];                        // b1
  }
  if (n == 0) {
    double c0 = (double)g2b[0];
    for (int o = 0; o < 16; ++o) c0 += (double)g2w[o] * (double)bet[o];
    P[32] = c0;
  }
}

// K2: pairwise dist_mean (f64) -> strict-lower adjacency bits, ballot-packed
__global__ __launch_bounds__(256) void k2_dist(
    const double* __restrict__ A, const double* __restrict__ P,
    unsigned long long* __restrict__ adjw) {
  int gw = blockIdx.x * 4 + (threadIdx.x >> 6);
  int lane = threadIdx.x & 63;
  int r = gw / NW, j = gw % NW;
  int c = j * 64 + lane;
  double x1 = 0.0, x2 = 0.0;
#pragma unroll
  for (int o = 0; o < 16; ++o) {
    double s = A[o * N_PED + r] - A[o * N_PED + c];
    double b = P[16 + o], w2 = P[o];
    x1 += w2 * fmax(s + b, 0.0);
    x2 += w2 * fmax(b - s, 0.0);
  }
  double c0 = P[32];
  double dist = 0.5 * (exp(x1 + c0) + exp(x2 + c0));
  bool bit = (c < r) && (dist <= 1.0);
  unsigned long long word = __ballot(bit ? 1 : 0);
  if (lane == 0) adjw[r * NW + j] = word;
}

// K3: faithful serial relabeling via value-map T (identical semantics to R1):
// per row r, every T entry with value in {L} u C_r -> cm = max(C_r).
// NEW: adjacency row words are STATIC, so prefetch row r+1's 24 u32 words
// into lanes 0..23 (+ rowcm[r+1] in lane 24) one row ahead; the Treg-dependent
// membership test uses only cross-lane shfl (bpermute), keeping LDS latency
// off the row-to-row serial chain. v==L is folded by OR-ing bit L into the
// row words.
__global__ __launch_bounds__(64) void k3_group(
    const unsigned long long* __restrict__ adjw, int* __restrict__ out_idx) {
  __shared__ unsigned int adjL[N_PED * 24];  // u32 view, 72 KB
  __shared__ int rowcmL[N_PED];
  __shared__ int flagsL[N_PED];
  __shared__ int rankL[N_PED];
  const int lane = threadIdx.x;

  // preload adjacency into LDS
  const unsigned int* adjg = (const unsigned int*)adjw;
  for (int i = lane; i < N_PED * 24; i += 64) adjL[i] = adjg[i];
  __syncthreads();

  // per-row max edge column (or -1)
#pragma unroll
  for (int k = 0; k < NW; ++k) {
    int r = k * 64 + lane;
    int cm = -1;
    for (int j = 23; j >= 0; --j) {
      unsigned w = adjL[r * 24 + j];
      if (w) { cm = j * 32 + (31 - __clz(w)); break; }
    }
    rowcmL[r] = cm;
  }
  __syncthreads();

  // value map in registers: Treg[k] = T[k*64 + lane]
  int Treg[NW];
#pragma unroll
  for (int k = 0; k < NW; ++k) Treg[k] = k * 64 + lane;

  // prefetch helper: lanes 0..23 -> row words, lane >=24 -> rowcm of the row
  auto pf_load = [&](int row) -> unsigned {
    if (lane < 24) return adjL[row * 24 + lane];
    return (unsigned)rowcmL[row];
  };

  unsigned wcur = pf_load(1);
  int cm_s = __builtin_amdgcn_readlane(wcur, 24);  // forces wait; SGPR

#pragma unroll
  for (int k0 = 0; k0 < NW; ++k0) {
    for (int rl = (k0 == 0 ? 1 : 0); rl < 64; ++rl) {
      int r = k0 * 64 + rl;
      // issue prefetch for next row (clamped); latency hides under body
      int rn = (r < N_PED - 1) ? r + 1 : N_PED - 1;
      unsigned wnext = pf_load(rn);
      int cm = cm_s;
      if (cm >= 0) {
        int L = __shfl(Treg[k0], rl);  // current label of node r
        unsigned wv = wcur | ((lane == (L >> 5)) ? (1u << (L & 31)) : 0u);
#pragma unroll
        for (int k = 0; k < NW; ++k) {
          int v = Treg[k];
          unsigned w = __shfl(wv, v >> 5);
          bool mem = ((w >> (v & 31)) & 1u) != 0u;
          Treg[k] = mem ? cm : Treg[k];
        }
      }
      wcur = wnext;
      cm_s = __builtin_amdgcn_readlane(wnext, 24);
    }
  }

  // rank distinct label values ascending -> group indices
#pragma unroll
  for (int k = 0; k < NW; ++k) flagsL[k * 64 + lane] = 0;
  __syncthreads();
#pragma unroll
  for (int k = 0; k < NW; ++k) flagsL[Treg[k]] = 1;
  __syncthreads();
  int f[NW];
  int s = 0;
#pragma unroll
  for (int q = 0; q < NW; ++q) { f[q] = flagsL[lane * NW + q]; s += f[q]; }
  int inc = s;
  for (int d = 1; d < 64; d <<= 1) {
    int t = __shfl_up(inc, d);
    if (lane >= d) inc += t;
  }
  int run = inc - s;  // exclusive prefix over lane segments
#pragma unroll
  for (int q = 0; q < NW; ++q) {
    run += f[q];
    rankL[lane * NW + q] = run - 1;
  }
  __syncthreads();
#pragma unroll
  for (int k = 0; k < NW; ++k) out_idx[k * 64 + lane] = rankL[Treg[k]];
}

// K4: deterministic group-mean pooling. block = one (c,t); thread = group slot g.
__global__ __launch_bounds__(768) void k4_pool(
    const float* __restrict__ vrel, const int* __restrict__ idx,
    float* __restrict__ pool) {
  int ct = blockIdx.x;
  int g = threadIdx.x;
  __shared__ int idxs[N_PED];
  __shared__ float vs[N_PED];
  idxs[g] = idx[g];
  vs[g] = vrel[ct * N_PED + g];
  __syncthreads();
  float s = 0.f;
  int cnt = 0;
  for (int n = 0; n < N_PED; ++n) {
    bool m = (idxs[n] == g);
    s += m ? vs[n] : 0.f;
    cnt += m ? 1 : 0;
  }
  pool[ct * N_PED + g] = s / fmaxf((float)cnt, 1.0f);
}

// K5: out[o,p,n] = (2*baseline(v_rel) + baseline(pool)[..,idx[n]]) / 3
__global__ __launch_bounds__(256) void k5_final(
    const float* __restrict__ vrel, const float* __restrict__ pool,
    const int* __restrict__ idx, const float* __restrict__ wt,
    const float* __restrict__ wc, float* __restrict__ out) {
  int i = blockIdx.x * 256 + threadIdx.x;
  if (i >= 5 * 12 * N_PED) return;
  int n = i % N_PED;
  int t_ = i / N_PED;
  int p = t_ % 12;
  int o = t_ / 12;
  int g = idx[n];
  float v1 = 0.f, v2 = 0.f;
#pragma unroll
  for (int c = 0; c < 2; ++c) {
    float u1 = 0.f, u2 = 0.f;
#pragma unroll
    for (int t = 0; t < 8; ++t) {
      float wtv = wt[t * 12 + p];
      u1 += wtv * vrel[(c * 8 + t) * N_PED + n];
      u2 += wtv * pool[(c * 8 + t) * N_PED + g];
    }
    float wcv = wc[c * 5 + o];
    v1 += wcv * u1;
    v2 += wcv * u2;
  }
  out[i] = (v1 + v2 + v1) / 3.0f;
}

extern "C" void kernel_launch(void* const* d_in, const int* in_sizes, int n_in,
                              void* d_out, int out_size, void* d_ws, size_t ws_size,
                              hipStream_t stream) {
  const float* va   = (const float*)d_in[0];
  const float* vr   = (const float*)d_in[1];
  const float* velw = (const float*)d_in[2];
  const float* velb = (const float*)d_in[3];
  const float* g1w  = (const float*)d_in[4];
  const float* g1b  = (const float*)d_in[5];
  const float* gam  = (const float*)d_in[6];
  const float* bet  = (const float*)d_in[7];
  const float* g2w  = (const float*)d_in[8];
  const float* g2b  = (const float*)d_in[9];
  const float* wt   = (const float*)d_in[10];
  const float* wc   = (const float*)d_in[11];
  float* out = (float*)d_out;

  char* ws = (char*)d_ws;
  double* A = (double*)(ws + 0);
  double* P = (double*)(ws + 98304);
  unsigned long long* adjw = (unsigned long long*)(ws + 98568);
  int* idx = (int*)(ws + 172296);
  float* pool = (float*)(ws + 175368);

  k1_prep<<<3, 256, 0, stream>>>(va, vr, velw, velb, g1w, g1b, gam, bet, g2w, g2b, A, P);
  k2_dist<<<2304, 256, 0, stream>>>(A, P, adjw);
  k3_group<<<1, 64, 0, stream>>>(adjw, idx);
  k4_pool<<<16, 768, 0, stream>>>(vr, idx, pool);
  k5_final<<<180, 256, 0, stream>>>(vr, pool, idx, wt, wc, out);
}

// Round 4
// 201.144 us; speedup vs baseline: 1.9944x; 1.9944x over previous
//
#include <hip/hip_runtime.h>
#include <math.h>

#define N_PED 768
#define NW 12  // 768/64 u64 words per adjacency row

// ---------------- ws layout (bytes) ----------------
// A      : [16][768] double   @ 0        (98304)
// P      : [33] double        @ 98304    (264)
// adjw   : [768*12] u64       @ 98568    (73728)   row-major bits
// adjT   : [768*12] u64       @ 172296   (73728)   column-major bits
// idx    : [768] int          @ 246024   (3072)
// pool   : [16][768] float    @ 249096   (49152)   -> ends 298248

// K1: per-pedestrian features -> A[o][n] = sum_k g1_w[o,k]*F[n,k]  (f64)
__global__ __launch_bounds__(256) void k1_prep(
    const float* __restrict__ va, const float* __restrict__ vr,
    const float* __restrict__ velw, const float* __restrict__ velb,
    const float* __restrict__ g1w, const float* __restrict__ g1b,
    const float* __restrict__ gam, const float* __restrict__ bet,
    const float* __restrict__ g2w, const float* __restrict__ g2b,
    double* __restrict__ A, double* __restrict__ P) {
  int n = blockIdx.x * 256 + threadIdx.x;
  if (n >= N_PED) return;
  double F[32];
#pragma unroll
  for (int c = 0; c < 2; ++c)
#pragma unroll
    for (int t = 0; t < 8; ++t)
      F[c * 8 + t] = (double)va[(c * 8 + t) * N_PED + n];
#pragma unroll
  for (int o = 0; o < 2; ++o)
#pragma unroll
    for (int t = 0; t < 8; ++t)
      F[(2 + o) * 8 + t] = (double)velb[o]
          + (double)velw[o * 2 + 0] * (double)vr[(0 + t) * N_PED + n]
          + (double)velw[o * 2 + 1] * (double)vr[(8 + t) * N_PED + n];
  for (int o = 0; o < 16; ++o) {
    double s = 0.0;
#pragma unroll
    for (int k = 0; k < 32; ++k) s += (double)g1w[o * 32 + k] * F[k];
    A[o * N_PED + n] = s;
  }
  if (n < 16) {
    const double inv_std = 1.0 / sqrt(1.0 + 1e-5);
    P[n] = (double)g2w[n] * inv_std * (double)gam[n];  // w2eff
    P[16 + n] = (double)g1b[n];                        // b1
  }
  if (n == 0) {
    double c0 = (double)g2b[0];
    for (int o = 0; o < 16; ++o) c0 += (double)g2w[o] * (double)bet[o];
    P[32] = c0;
  }
}

// K2: pairwise dist_mean (f64) -> strict-lower adjacency bits, ballot-packed
__global__ __launch_bounds__(256) void k2_dist(
    const double* __restrict__ A, const double* __restrict__ P,
    unsigned long long* __restrict__ adjw) {
  int gw = blockIdx.x * 4 + (threadIdx.x >> 6);
  int lane = threadIdx.x & 63;
  int r = gw / NW, j = gw % NW;
  int c = j * 64 + lane;
  double x1 = 0.0, x2 = 0.0;
#pragma unroll
  for (int o = 0; o < 16; ++o) {
    double s = A[o * N_PED + r] - A[o * N_PED + c];
    double b = P[16 + o], w2 = P[o];
    x1 += w2 * fmax(s + b, 0.0);
    x2 += w2 * fmax(b - s, 0.0);
  }
  double c0 = P[32];
  double dist = 0.5 * (exp(x1 + c0) + exp(x2 + c0));
  bool bit = (c < r) && (dist <= 1.0);
  unsigned long long word = __ballot(bit ? 1 : 0);
  if (lane == 0) adjw[r * NW + j] = word;
}

// K2T: 64x64 bit-tile transpose via ballots. 144 tiles, one wave each.
__global__ __launch_bounds__(256) void k2t(
    const unsigned long long* __restrict__ adjw,
    unsigned long long* __restrict__ adjT) {
  int wid = blockIdx.x * 4 + (threadIdx.x >> 6);
  int lane = threadIdx.x & 63;
  int I = wid / NW, J = wid % NW;  // row-tile, col-tile
  unsigned long long w = adjw[(I * 64 + lane) * NW + J];
  unsigned long long mine = 0;
#pragma unroll
  for (int b = 0; b < 64; ++b) {
    unsigned long long t = __ballot((w >> b) & 1ull);
    if (lane == b) mine = t;
  }
  adjT[(J * 64 + lane) * NW + I] = mine;
}

// K3: per-node independent chain following.
// Invariant (proved): when row r processes, labels[r]==r, so row r's op is
// "values in C_r u {r} -> cm_r = max(C_r)". A node's final label follows:
//   (v,r) = rowcm[n]>=0 ? (rowcm[n], n) : (n, n)
//   while exists r' > r with adjT[v] bit r' set:  r = r'; v = rowcm[r];
// r strictly increases -> <=767 steps; all 768 nodes fully parallel.
__global__ __launch_bounds__(768) void k3_chain(
    const unsigned long long* __restrict__ adjw,
    const unsigned long long* __restrict__ adjT,
    int* __restrict__ out_idx) {
  __shared__ unsigned long long adjTL[N_PED * NW];  // 72 KB
  __shared__ int rowcmL[N_PED];
  __shared__ int labL[N_PED];
  __shared__ int rankL[N_PED];
  const int n = threadIdx.x;

  for (int i = n; i < N_PED * NW; i += 768) adjTL[i] = adjT[i];
  int cm = -1;
  for (int j = NW - 1; j >= 0; --j) {
    unsigned long long w = adjw[n * NW + j];
    if (w) { cm = j * 64 + 63 - __clzll((long long)w); break; }
  }
  rowcmL[n] = cm;
  __syncthreads();

  int v = n, r = n;
  if (cm >= 0) v = cm;
  for (;;) {
    int j = r >> 6, rl = r & 63;
    unsigned long long w = (adjTL[v * NW + j] >> rl) >> 1;  // bits strictly above r
    int rn;
    if (w) {
      rn = r + __ffsll(w);  // r + 1 + (ctz)
    } else {
      rn = -1;
      for (++j; j < NW; ++j) {
        unsigned long long ww = adjTL[v * NW + j];
        if (ww) { rn = j * 64 + __ffsll(ww) - 1; break; }
      }
      if (rn < 0) break;
    }
    r = rn;
    v = rowcmL[r];
  }
  labL[n] = v;
  __syncthreads();

  // rank distinct label values ascending -> group indices
  rowcmL[n] = 0;  // reuse as flags
  __syncthreads();
  rowcmL[labL[n]] = 1;
  __syncthreads();
  if (n < 64) {  // wave 0 does the 12-segment scan
    int f[NW], s = 0;
#pragma unroll
    for (int q = 0; q < NW; ++q) { f[q] = rowcmL[n * NW + q]; s += f[q]; }
    int inc = s;
    for (int d = 1; d < 64; d <<= 1) {
      int t = __shfl_up(inc, d);
      if (n >= d) inc += t;
    }
    int run = inc - s;
#pragma unroll
    for (int q = 0; q < NW; ++q) { run += f[q]; rankL[n * NW + q] = run - 1; }
  }
  __syncthreads();
  out_idx[n] = rankL[labL[n]];
}

// K4: deterministic group-mean pooling. block = one (c,t); thread = group slot g.
__global__ __launch_bounds__(768) void k4_pool(
    const float* __restrict__ vrel, const int* __restrict__ idx,
    float* __restrict__ pool) {
  int ct = blockIdx.x;
  int g = threadIdx.x;
  __shared__ int idxs[N_PED];
  __shared__ float vs[N_PED];
  idxs[g] = idx[g];
  vs[g] = vrel[ct * N_PED + g];
  __syncthreads();
  float s = 0.f;
  int cnt = 0;
  for (int n = 0; n < N_PED; ++n) {
    bool m = (idxs[n] == g);
    s += m ? vs[n] : 0.f;
    cnt += m ? 1 : 0;
  }
  pool[ct * N_PED + g] = s / fmaxf((float)cnt, 1.0f);
}

// K5: out[o,p,n] = (2*baseline(v_rel) + baseline(pool)[..,idx[n]]) / 3
__global__ __launch_bounds__(256) void k5_final(
    const float* __restrict__ vrel, const float* __restrict__ pool,
    const int* __restrict__ idx, const float* __restrict__ wt,
    const float* __restrict__ wc, float* __restrict__ out) {
  int i = blockIdx.x * 256 + threadIdx.x;
  if (i >= 5 * 12 * N_PED) return;
  int n = i % N_PED;
  int t_ = i / N_PED;
  int p = t_ % 12;
  int o = t_ / 12;
  int g = idx[n];
  float v1 = 0.f, v2 = 0.f;
#pragma unroll
  for (int c = 0; c < 2; ++c) {
    float u1 = 0.f, u2 = 0.f;
#pragma unroll
    for (int t = 0; t < 8; ++t) {
      float wtv = wt[t * 12 + p];
      u1 += wtv * vrel[(c * 8 + t) * N_PED + n];
      u2 += wtv * pool[(c * 8 + t) * N_PED + g];
    }
    float wcv = wc[c * 5 + o];
    v1 += wcv * u1;
    v2 += wcv * u2;
  }
  out[i] = (v1 + v2 + v1) / 3.0f;
}

extern "C" void kernel_launch(void* const* d_in, const int* in_sizes, int n_in,
                              void* d_out, int out_size, void* d_ws, size_t ws_size,
                              hipStream_t stream) {
  const float* va   = (const float*)d_in[0];
  const float* vr   = (const float*)d_in[1];
  const float* velw = (const float*)d_in[2];
  const float* velb = (const float*)d_in[3];
  const float* g1w  = (const float*)d_in[4];
  const float* g1b  = (const float*)d_in[5];
  const float* gam  = (const float*)d_in[6];
  const float* bet  = (const float*)d_in[7];
  const float* g2w  = (const float*)d_in[8];
  const float* g2b  = (const float*)d_in[9];
  const float* wt   = (const float*)d_in[10];
  const float* wc   = (const float*)d_in[11];
  float* out = (float*)d_out;

  char* ws = (char*)d_ws;
  double* A = (double*)(ws + 0);
  double* P = (double*)(ws + 98304);
  unsigned long long* adjw = (unsigned long long*)(ws + 98568);
  unsigned long long* adjT = (unsigned long long*)(ws + 172296);
  int* idx = (int*)(ws + 246024);
  float* pool = (float*)(ws + 249096);

  k1_prep<<<3, 256, 0, stream>>>(va, vr, velw, velb, g1w, g1b, gam, bet, g2w, g2b, A, P);
  k2_dist<<<2304, 256, 0, stream>>>(A, P, adjw);
  k2t<<<36, 256, 0, stream>>>(adjw, adjT);
  k3_chain<<<1, 768, 0, stream>>>(adjw, adjT, idx);
  k4_pool<<<16, 768, 0, stream>>>(vr, idx, pool);
  k5_final<<<180, 256, 0, stream>>>(vr, pool, idx, wt, wc, out);
}

// Round 5
// 78.522 us; speedup vs baseline: 5.1089x; 2.5616x over previous
//
#include <hip/hip_runtime.h>
#include <math.h>

#define N_PED 768
#define NW 12  // 768/64 u64 words per adjacency row

// ---------------- ws layout (bytes) ----------------
// A      : [16][768] double   @ 0        (98304)
// P      : [33] double        @ 98304    (264)
// adjw   : [768*12] u64       @ 98568    (73728)   row-major bits
// adjT   : [768*12] u64       @ 172296   (73728)   column-major bits
// idx    : [768] int          @ 246024   (3072)
// pool   : [16][768] float    @ 249096   (49152)   -> ends 298248

// K1: per-pedestrian features -> A[o][n] = sum_k g1_w[o,k]*F[n,k]  (f64)
__global__ __launch_bounds__(256) void k1_prep(
    const float* __restrict__ va, const float* __restrict__ vr,
    const float* __restrict__ velw, const float* __restrict__ velb,
    const float* __restrict__ g1w, const float* __restrict__ g1b,
    const float* __restrict__ gam, const float* __restrict__ bet,
    const float* __restrict__ g2w, const float* __restrict__ g2b,
    double* __restrict__ A, double* __restrict__ P) {
  int n = blockIdx.x * 256 + threadIdx.x;
  if (n >= N_PED) return;
  double F[32];
#pragma unroll
  for (int c = 0; c < 2; ++c)
#pragma unroll
    for (int t = 0; t < 8; ++t)
      F[c * 8 + t] = (double)va[(c * 8 + t) * N_PED + n];
#pragma unroll
  for (int o = 0; o < 2; ++o)
#pragma unroll
    for (int t = 0; t < 8; ++t)
      F[(2 + o) * 8 + t] = (double)velb[o]
          + (double)velw[o * 2 + 0] * (double)vr[(0 + t) * N_PED + n]
          + (double)velw[o * 2 + 1] * (double)vr[(8 + t) * N_PED + n];
  for (int o = 0; o < 16; ++o) {
    double s = 0.0;
#pragma unroll
    for (int k = 0; k < 32; ++k) s += (double)g1w[o * 32 + k] * F[k];
    A[o * N_PED + n] = s;
  }
  if (n < 16) {
    const double inv_std = 1.0 / sqrt(1.0 + 1e-5);
    P[n] = (double)g2w[n] * inv_std * (double)gam[n];  // w2eff
    P[16 + n] = (double)g1b[n];                        // b1
  }
  if (n == 0) {
    double c0 = (double)g2b[0];
    for (int o = 0; o < 16; ++o) c0 += (double)g2w[o] * (double)bet[o];
    P[32] = c0;
  }
}

// K2: pairwise dist_mean (f64) -> strict-lower adjacency bits, ballot-packed
__global__ __launch_bounds__(256) void k2_dist(
    const double* __restrict__ A, const double* __restrict__ P,
    unsigned long long* __restrict__ adjw) {
  int gw = blockIdx.x * 4 + (threadIdx.x >> 6);
  int lane = threadIdx.x & 63;
  int r = gw / NW, j = gw % NW;
  int c = j * 64 + lane;
  double x1 = 0.0, x2 = 0.0;
#pragma unroll
  for (int o = 0; o < 16; ++o) {
    double s = A[o * N_PED + r] - A[o * N_PED + c];
    double b = P[16 + o], w2 = P[o];
    x1 += w2 * fmax(s + b, 0.0);
    x2 += w2 * fmax(b - s, 0.0);
  }
  double c0 = P[32];
  double dist = 0.5 * (exp(x1 + c0) + exp(x2 + c0));
  bool bit = (c < r) && (dist <= 1.0);
  unsigned long long word = __ballot(bit ? 1 : 0);
  if (lane == 0) adjw[r * NW + j] = word;
}

// K2T: 64x64 bit-tile transpose via ballots. 144 tiles, one wave each.
__global__ __launch_bounds__(256) void k2t(
    const unsigned long long* __restrict__ adjw,
    unsigned long long* __restrict__ adjT) {
  int wid = blockIdx.x * 4 + (threadIdx.x >> 6);
  int lane = threadIdx.x & 63;
  int I = wid / NW, J = wid % NW;  // row-tile, col-tile
  unsigned long long w = adjw[(I * 64 + lane) * NW + J];
  unsigned long long mine = 0;
#pragma unroll
  for (int b = 0; b < 64; ++b) {
    unsigned long long t = __ballot((w >> b) & 1ull);
    if (lane == b) mine = t;
  }
  adjT[(J * 64 + lane) * NW + I] = mine;
}

// K3: pointer-doubling over the successor forest.
// Exact semantics (proved): label(n) = label(succ(n)) where
//   v0[n]   = rowcm[n] >= 0 ? rowcm[n] : n
//   succ(n) = first set bit in column v0[n] strictly below row n (self if none)
//   label(root) = v0[root]
// because the chain state after jumping to row r' equals node r''s own start
// state (rowcm[r'], r'). Forest edges point upward -> 10 rounds of jumping.
__global__ __launch_bounds__(768) void k3_jump(
    const unsigned long long* __restrict__ adjw,
    const unsigned long long* __restrict__ adjT,
    int* __restrict__ out_idx) {
  __shared__ unsigned long long adjTL[N_PED * NW];  // 72 KB
  __shared__ int nxtA[N_PED], nxtB[N_PED];
  __shared__ int valL[N_PED], labL[N_PED], rankL[N_PED];
  const int n = threadIdx.x;

  for (int i = n; i < N_PED * NW; i += 768) adjTL[i] = adjT[i];
  // rowcm from row-major bits (global; independent per thread)
  int cm = -1;
  for (int j = NW - 1; j >= 0; --j) {
    unsigned long long w = adjw[n * NW + j];
    if (w) { cm = j * 64 + 63 - __clzll((long long)w); break; }
  }
  int v0 = (cm >= 0) ? cm : n;
  valL[n] = v0;
  __syncthreads();

  // succ: first set bit in column v0 strictly after row n (self if none)
  int succ = n;
  {
    int j = n >> 6, rl = n & 63;
    unsigned long long w = (adjTL[v0 * NW + j] >> rl) >> 1;
    if (w) {
      succ = n + __ffsll(w);
    } else {
      for (++j; j < NW; ++j) {
        unsigned long long ww = adjTL[v0 * NW + j];
        if (ww) { succ = j * 64 + __ffsll(ww) - 1; break; }
      }
    }
  }
  nxtA[n] = succ;
  __syncthreads();

  // 10 rounds of pointer jumping (2^10 >= 767)
  int* src = nxtA;
  int* dst = nxtB;
#pragma unroll
  for (int it = 0; it < 10; ++it) {
    dst[n] = src[src[n]];
    __syncthreads();
    int* t = src; src = dst; dst = t;
  }
  labL[n] = valL[src[n]];
  __syncthreads();

  // rank distinct label values ascending -> group indices
  nxtA[n] = 0;  // reuse as flags
  __syncthreads();
  nxtA[labL[n]] = 1;
  __syncthreads();
  if (n < 64) {  // wave 0: 12-segment scan
    int f[NW], s = 0;
#pragma unroll
    for (int q = 0; q < NW; ++q) { f[q] = nxtA[n * NW + q]; s += f[q]; }
    int inc = s;
    for (int d = 1; d < 64; d <<= 1) {
      int t = __shfl_up(inc, d);
      if (n >= d) inc += t;
    }
    int run = inc - s;
#pragma unroll
    for (int q = 0; q < NW; ++q) { run += f[q]; rankL[n * NW + q] = run - 1; }
  }
  __syncthreads();
  out_idx[n] = rankL[labL[n]];
}

// K4: deterministic group-mean pooling. block = one (c,t); thread = group slot g.
__global__ __launch_bounds__(768) void k4_pool(
    const float* __restrict__ vrel, const int* __restrict__ idx,
    float* __restrict__ pool) {
  int ct = blockIdx.x;
  int g = threadIdx.x;
  __shared__ int idxs[N_PED];
  __shared__ float vs[N_PED];
  idxs[g] = idx[g];
  vs[g] = vrel[ct * N_PED + g];
  __syncthreads();
  float s = 0.f;
  int cnt = 0;
  for (int n = 0; n < N_PED; ++n) {
    bool m = (idxs[n] == g);
    s += m ? vs[n] : 0.f;
    cnt += m ? 1 : 0;
  }
  pool[ct * N_PED + g] = s / fmaxf((float)cnt, 1.0f);
}

// K5: out[o,p,n] = (2*baseline(v_rel) + baseline(pool)[..,idx[n]]) / 3
__global__ __launch_bounds__(256) void k5_final(
    const float* __restrict__ vrel, const float* __restrict__ pool,
    const int* __restrict__ idx, const float* __restrict__ wt,
    const float* __restrict__ wc, float* __restrict__ out) {
  int i = blockIdx.x * 256 + threadIdx.x;
  if (i >= 5 * 12 * N_PED) return;
  int n = i % N_PED;
  int t_ = i / N_PED;
  int p = t_ % 12;
  int o = t_ / 12;
  int g = idx[n];
  float v1 = 0.f, v2 = 0.f;
#pragma unroll
  for (int c = 0; c < 2; ++c) {
    float u1 = 0.f, u2 = 0.f;
#pragma unroll
    for (int t = 0; t < 8; ++t) {
      float wtv = wt[t * 12 + p];
      u1 += wtv * vrel[(c * 8 + t) * N_PED + n];
      u2 += wtv * pool[(c * 8 + t) * N_PED + g];
    }
    float wcv = wc[c * 5 + o];
    v1 += wcv * u1;
    v2 += wcv * u2;
  }
  out[i] = (v1 + v2 + v1) / 3.0f;
}

extern "C" void kernel_launch(void* const* d_in, const int* in_sizes, int n_in,
                              void* d_out, int out_size, void* d_ws, size_t ws_size,
                              hipStream_t stream) {
  const float* va   = (const float*)d_in[0];
  const float* vr   = (const float*)d_in[1];
  const float* velw = (const float*)d_in[2];
  const float* velb = (const float*)d_in[3];
  const float* g1w  = (const float*)d_in[4];
  const float* g1b  = (const float*)d_in[5];
  const float* gam  = (const float*)d_in[6];
  const float* bet  = (const float*)d_in[7];
  const float* g2w  = (const float*)d_in[8];
  const float* g2b  = (const float*)d_in[9];
  const float* wt   = (const float*)d_in[10];
  const float* wc   = (const float*)d_in[11];
  float* out = (float*)d_out;

  char* ws = (char*)d_ws;
  double* A = (double*)(ws + 0);
  double* P = (double*)(ws + 98304);
  unsigned long long* adjw = (unsigned long long*)(ws + 98568);
  unsigned long long* adjT = (unsigned long long*)(ws + 172296);
  int* idx = (int*)(ws + 246024);
  float* pool = (float*)(ws + 249096);

  k1_prep<<<3, 256, 0, stream>>>(va, vr, velw, velb, g1w, g1b, gam, bet, g2w, g2b, A, P);
  k2_dist<<<2304, 256, 0, stream>>>(A, P, adjw);
  k2t<<<36, 256, 0, stream>>>(adjw, adjT);
  k3_jump<<<1, 768, 0, stream>>>(adjw, adjT, idx);
  k4_pool<<<16, 768, 0, stream>>>(vr, idx, pool);
  k5_final<<<180, 256, 0, stream>>>(vr, pool, idx, wt, wc, out);
}

// Round 6
// 38.872 us; speedup vs baseline: 10.3201x; 2.0200x over previous
//
#include <hip/hip_runtime.h>
#include <math.h>

#define N_PED 768
#define NW 12  // 768/64 u64 words per adjacency row

// ---------------- ws layout (bytes) ----------------
// A      : [16][768] double   @ 0        (98304)
// P      : [33] double        @ 98304    (264)
// adjw   : [768*12] u64       @ 98568    (73728)   row-major bits
// adjT   : [768*12] u64       @ 172296   (73728)   column-major bits
// idx    : [768] int          @ 246024   (3072)
// pool   : [16][768] float    @ 249096   (49152)   -> ends 298248

// K1: per-pedestrian features -> A[o][n] = sum_k g1_w[o,k]*F[n,k]  (f64)
__global__ __launch_bounds__(256) void k1_prep(
    const float* __restrict__ va, const float* __restrict__ vr,
    const float* __restrict__ velw, const float* __restrict__ velb,
    const float* __restrict__ g1w, const float* __restrict__ g1b,
    const float* __restrict__ gam, const float* __restrict__ bet,
    const float* __restrict__ g2w, const float* __restrict__ g2b,
    double* __restrict__ A, double* __restrict__ P) {
  int n = blockIdx.x * 256 + threadIdx.x;
  if (n >= N_PED) return;
  double F[32];
#pragma unroll
  for (int c = 0; c < 2; ++c)
#pragma unroll
    for (int t = 0; t < 8; ++t)
      F[c * 8 + t] = (double)va[(c * 8 + t) * N_PED + n];
#pragma unroll
  for (int o = 0; o < 2; ++o)
#pragma unroll
    for (int t = 0; t < 8; ++t)
      F[(2 + o) * 8 + t] = (double)velb[o]
          + (double)velw[o * 2 + 0] * (double)vr[(0 + t) * N_PED + n]
          + (double)velw[o * 2 + 1] * (double)vr[(8 + t) * N_PED + n];
  for (int o = 0; o < 16; ++o) {
    double s = 0.0;
#pragma unroll
    for (int k = 0; k < 32; ++k) s += (double)g1w[o * 32 + k] * F[k];
    A[o * N_PED + n] = s;
  }
  if (n < 16) {
    const double inv_std = 1.0 / sqrt(1.0 + 1e-5);
    P[n] = (double)g2w[n] * inv_std * (double)gam[n];  // w2eff
    P[16 + n] = (double)g1b[n];                        // b1
  }
  if (n == 0) {
    double c0 = (double)g2b[0];
    for (int o = 0; o < 16; ++o) c0 += (double)g2w[o] * (double)bet[o];
    P[32] = c0;
  }
}

// K2: pairwise dist_mean (f64) -> strict-lower adjacency bits, ballot-packed
__global__ __launch_bounds__(256) void k2_dist(
    const double* __restrict__ A, const double* __restrict__ P,
    unsigned long long* __restrict__ adjw) {
  int gw = blockIdx.x * 4 + (threadIdx.x >> 6);
  int lane = threadIdx.x & 63;
  int r = gw / NW, j = gw % NW;
  int c = j * 64 + lane;
  double x1 = 0.0, x2 = 0.0;
#pragma unroll
  for (int o = 0; o < 16; ++o) {
    double s = A[o * N_PED + r] - A[o * N_PED + c];
    double b = P[16 + o], w2 = P[o];
    x1 += w2 * fmax(s + b, 0.0);
    x2 += w2 * fmax(b - s, 0.0);
  }
  double c0 = P[32];
  double dist = 0.5 * (exp(x1 + c0) + exp(x2 + c0));
  bool bit = (c < r) && (dist <= 1.0);
  unsigned long long word = __ballot(bit ? 1 : 0);
  if (lane == 0) adjw[r * NW + j] = word;
}

// K2T: 64x64 bit-tile transpose via ballots. 144 tiles, one wave each.
__global__ __launch_bounds__(256) void k2t(
    const unsigned long long* __restrict__ adjw,
    unsigned long long* __restrict__ adjT) {
  int wid = blockIdx.x * 4 + (threadIdx.x >> 6);
  int lane = threadIdx.x & 63;
  int I = wid / NW, J = wid % NW;  // row-tile, col-tile
  unsigned long long w = adjw[(I * 64 + lane) * NW + J];
  unsigned long long mine = 0;
#pragma unroll
  for (int b = 0; b < 64; ++b) {
    unsigned long long t = __ballot((w >> b) & 1ull);
    if (lane == b) mine = t;
  }
  adjT[(J * 64 + lane) * NW + I] = mine;
}

// K3: pointer-doubling over the successor forest.
// Exact semantics (proved): label(n) = label(succ(n)) where
//   v0[n]   = rowcm[n] >= 0 ? rowcm[n] : n
//   succ(n) = first set bit in column v0[n] strictly below row n (self if none)
//   label(root) = v0[root]
__global__ __launch_bounds__(768) void k3_jump(
    const unsigned long long* __restrict__ adjw,
    const unsigned long long* __restrict__ adjT,
    int* __restrict__ out_idx) {
  __shared__ unsigned long long adjTL[N_PED * NW];  // 72 KB
  __shared__ int nxtA[N_PED], nxtB[N_PED];
  __shared__ int valL[N_PED], labL[N_PED], rankL[N_PED];
  const int n = threadIdx.x;

  for (int i = n; i < N_PED * NW; i += 768) adjTL[i] = adjT[i];
  // rowcm from row-major bits (global; independent per thread)
  int cm = -1;
  for (int j = NW - 1; j >= 0; --j) {
    unsigned long long w = adjw[n * NW + j];
    if (w) { cm = j * 64 + 63 - __clzll((long long)w); break; }
  }
  int v0 = (cm >= 0) ? cm : n;
  valL[n] = v0;
  __syncthreads();

  // succ: first set bit in column v0 strictly after row n (self if none)
  int succ = n;
  {
    int j = n >> 6, rl = n & 63;
    unsigned long long w = (adjTL[v0 * NW + j] >> rl) >> 1;
    if (w) {
      succ = n + __ffsll(w);
    } else {
      for (++j; j < NW; ++j) {
        unsigned long long ww = adjTL[v0 * NW + j];
        if (ww) { succ = j * 64 + __ffsll(ww) - 1; break; }
      }
    }
  }
  nxtA[n] = succ;
  __syncthreads();

  // 10 rounds of pointer jumping (2^10 >= 767)
  int* src = nxtA;
  int* dst = nxtB;
#pragma unroll
  for (int it = 0; it < 10; ++it) {
    dst[n] = src[src[n]];
    __syncthreads();
    int* t = src; src = dst; dst = t;
  }
  labL[n] = valL[src[n]];
  __syncthreads();

  // rank distinct label values ascending -> group indices
  nxtA[n] = 0;  // reuse as flags
  __syncthreads();
  nxtA[labL[n]] = 1;
  __syncthreads();
  if (n < 64) {  // wave 0: 12-segment scan
    int f[NW], s = 0;
#pragma unroll
    for (int q = 0; q < NW; ++q) { f[q] = nxtA[n * NW + q]; s += f[q]; }
    int inc = s;
    for (int d = 1; d < 64; d <<= 1) {
      int t = __shfl_up(inc, d);
      if (n >= d) inc += t;
    }
    int run = inc - s;
#pragma unroll
    for (int q = 0; q < NW; ++q) { run += f[q]; rankL[n * NW + q] = run - 1; }
  }
  __syncthreads();
  out_idx[n] = rankL[labL[n]];
}

// K4: group-mean pooling, one wave per (ct, g). 64 lanes split the 768-node
// scan (independent coalesced loads), then a deterministic shfl_xor tree
// reduce for sum and count. 12288 waves -> all CUs busy.
__global__ __launch_bounds__(256) void k4_pool(
    const float* __restrict__ vrel, const int* __restrict__ idx,
    float* __restrict__ pool) {
  int wv = blockIdx.x * 4 + (threadIdx.x >> 6);  // 0..12287
  int lane = threadIdx.x & 63;
  int ct = wv / N_PED;
  int g = wv % N_PED;
  float s = 0.f;
  int cnt = 0;
#pragma unroll
  for (int k = 0; k < NW; ++k) {
    int n = k * 64 + lane;
    int id = idx[n];
    float v = vrel[ct * N_PED + n];
    bool m = (id == g);
    s += m ? v : 0.f;
    cnt += m ? 1 : 0;
  }
#pragma unroll
  for (int d = 1; d < 64; d <<= 1) {
    s += __shfl_xor(s, d);
    cnt += __shfl_xor(cnt, d);
  }
  if (lane == 0) pool[ct * N_PED + g] = s / fmaxf((float)cnt, 1.0f);
}

// K5: out[o,p,n] = (2*baseline(v_rel) + baseline(pool)[..,idx[n]]) / 3
__global__ __launch_bounds__(256) void k5_final(
    const float* __restrict__ vrel, const float* __restrict__ pool,
    const int* __restrict__ idx, const float* __restrict__ wt,
    const float* __restrict__ wc, float* __restrict__ out) {
  int i = blockIdx.x * 256 + threadIdx.x;
  if (i >= 5 * 12 * N_PED) return;
  int n = i % N_PED;
  int t_ = i / N_PED;
  int p = t_ % 12;
  int o = t_ / 12;
  int g = idx[n];
  float v1 = 0.f, v2 = 0.f;
#pragma unroll
  for (int c = 0; c < 2; ++c) {
    float u1 = 0.f, u2 = 0.f;
#pragma unroll
    for (int t = 0; t < 8; ++t) {
      float wtv = wt[t * 12 + p];
      u1 += wtv * vrel[(c * 8 + t) * N_PED + n];
      u2 += wtv * pool[(c * 8 + t) * N_PED + g];
    }
    float wcv = wc[c * 5 + o];
    v1 += wcv * u1;
    v2 += wcv * u2;
  }
  out[i] = (v1 + v2 + v1) / 3.0f;
}

extern "C" void kernel_launch(void* const* d_in, const int* in_sizes, int n_in,
                              void* d_out, int out_size, void* d_ws, size_t ws_size,
                              hipStream_t stream) {
  const float* va   = (const float*)d_in[0];
  const float* vr   = (const float*)d_in[1];
  const float* velw = (const float*)d_in[2];
  const float* velb = (const float*)d_in[3];
  const float* g1w  = (const float*)d_in[4];
  const float* g1b  = (const float*)d_in[5];
  const float* gam  = (const float*)d_in[6];
  const float* bet  = (const float*)d_in[7];
  const float* g2w  = (const float*)d_in[8];
  const float* g2b  = (const float*)d_in[9];
  const float* wt   = (const float*)d_in[10];
  const float* wc   = (const float*)d_in[11];
  float* out = (float*)d_out;

  char* ws = (char*)d_ws;
  double* A = (double*)(ws + 0);
  double* P = (double*)(ws + 98304);
  unsigned long long* adjw = (unsigned long long*)(ws + 98568);
  unsigned long long* adjT = (unsigned long long*)(ws + 172296);
  int* idx = (int*)(ws + 246024);
  float* pool = (float*)(ws + 249096);

  k1_prep<<<3, 256, 0, stream>>>(va, vr, velw, velb, g1w, g1b, gam, bet, g2w, g2b, A, P);
  k2_dist<<<2304, 256, 0, stream>>>(A, P, adjw);
  k2t<<<36, 256, 0, stream>>>(adjw, adjT);
  k3_jump<<<1, 768, 0, stream>>>(adjw, adjT, idx);
  k4_pool<<<3072, 256, 0, stream>>>(vr, idx, pool);
  k5_final<<<180, 256, 0, stream>>>(vr, pool, idx, wt, wc, out);
}

// Round 7
// 35.867 us; speedup vs baseline: 11.1848x; 1.0838x over previous
//
#include <hip/hip_runtime.h>
#include <math.h>

#define N_PED 768
#define NW 12  // 768/64 u64 words per adjacency row

// ---------------- ws layout (bytes) ----------------
// A        : [16][768] double @ 0        (98304)
// P        : [33] double      @ 98304    (264, pad to 98568)
// adjT     : [768*12] u64     @ 98568    (73728)  column-major bits
// rowmax2d : [768*12] int     @ 172296   (36864)  per-tile row max col (or -1)
// idx      : [768] int        @ 209160   (3072)
// pool     : [16][768] float  @ 212232   (49152)  -> ends 261384

// K1: per-pedestrian features -> A[o][n] = sum_k g1_w[o,k]*F[n,k]  (f64)
__global__ __launch_bounds__(256) void k1_prep(
    const float* __restrict__ va, const float* __restrict__ vr,
    const float* __restrict__ velw, const float* __restrict__ velb,
    const float* __restrict__ g1w, const float* __restrict__ g1b,
    const float* __restrict__ gam, const float* __restrict__ bet,
    const float* __restrict__ g2w, const float* __restrict__ g2b,
    double* __restrict__ A, double* __restrict__ P) {
  int n = blockIdx.x * 256 + threadIdx.x;
  if (n >= N_PED) return;
  double F[32];
#pragma unroll
  for (int c = 0; c < 2; ++c)
#pragma unroll
    for (int t = 0; t < 8; ++t)
      F[c * 8 + t] = (double)va[(c * 8 + t) * N_PED + n];
#pragma unroll
  for (int o = 0; o < 2; ++o)
#pragma unroll
    for (int t = 0; t < 8; ++t)
      F[(2 + o) * 8 + t] = (double)velb[o]
          + (double)velw[o * 2 + 0] * (double)vr[(0 + t) * N_PED + n]
          + (double)velw[o * 2 + 1] * (double)vr[(8 + t) * N_PED + n];
  for (int o = 0; o < 16; ++o) {
    double s = 0.0;
#pragma unroll
    for (int k = 0; k < 32; ++k) s += (double)g1w[o * 32 + k] * F[k];
    A[o * N_PED + n] = s;
  }
  if (n < 16) {
    const double inv_std = 1.0 / sqrt(1.0 + 1e-5);
    P[n] = (double)g2w[n] * inv_std * (double)gam[n];  // w2eff
    P[16 + n] = (double)g1b[n];                        // b1
  }
  if (n == 0) {
    double c0 = (double)g2b[0];
    for (int o = 0; o < 16; ++o) c0 += (double)g2w[o] * (double)bet[o];
    P[32] = c0;
  }
}

// K2F: fused pairwise-dist + bit-transpose + per-tile row maxima.
// Block = one 64x64 tile (I = row-tile, J = col-tile). Upper tiles (I<J)
// are structurally zero (c<r constraint): just zero-fill adjT and rowmax2d.
// Lower/diagonal tiles: wave w handles rows w*16..w*16+15 (lane = col);
// ballot -> row word -> LDS; then ballot-transpose -> adjT words.
__global__ __launch_bounds__(256) void k2f(
    const double* __restrict__ A, const double* __restrict__ P,
    unsigned long long* __restrict__ adjT, int* __restrict__ rowmax2d) {
  int tile = blockIdx.x;
  int I = tile / NW, J = tile % NW;
  int w = threadIdx.x >> 6, lane = threadIdx.x & 63;
  if (I < J) {
    int t = threadIdx.x;
    if (t < 64) {
      adjT[(J * 64 + t) * NW + I] = 0ull;
      rowmax2d[(I * 64 + t) * NW + J] = -1;
    }
    return;
  }
  __shared__ unsigned long long roww[64];
  int c = J * 64 + lane;
  double Ac[16], b1[16], w2[16];
#pragma unroll
  for (int o = 0; o < 16; ++o) {
    Ac[o] = A[o * N_PED + c];
    w2[o] = P[o];
    b1[o] = P[16 + o];
  }
  double c0 = P[32];
  for (int q = 0; q < 16; ++q) {
    int rl = w * 16 + q;
    int r = I * 64 + rl;
    double x1 = 0.0, x2 = 0.0;
#pragma unroll
    for (int o = 0; o < 16; ++o) {
      double s = A[o * N_PED + r] - Ac[o];
      x1 += w2[o] * fmax(s + b1[o], 0.0);
      x2 += w2[o] * fmax(b1[o] - s, 0.0);
    }
    double dist = 0.5 * (exp(x1 + c0) + exp(x2 + c0));
    bool bit = (c < r) && (dist <= 1.0);
    unsigned long long word = __ballot(bit ? 1 : 0);
    if (lane == 0) {
      roww[rl] = word;
      rowmax2d[r * NW + J] =
          word ? (J * 64 + 63 - __clzll((long long)word)) : -1;
    }
  }
  __syncthreads();
  unsigned long long myrow = roww[lane];  // lane = source row
  for (int q = 0; q < 16; ++q) {
    int tc = w * 16 + q;
    unsigned long long tw = __ballot((myrow >> tc) & 1ull);
    if (lane == 0) adjT[(J * 64 + tc) * NW + I] = tw;
  }
}

// K3: pointer-doubling over the successor forest.
// Exact semantics (proved R4): label(n) = label(succ(n)) where
//   v0[n]   = rowcm[n] >= 0 ? rowcm[n] : n
//   succ(n) = first set bit in column v0[n] strictly below row n (self if none)
//   label(root) = v0[root]
// rowcm comes from a 12-wide max over rowmax2d (parallel, coalesced);
// succ scans adjT straight from L2 (usually 1-2 words).
__global__ __launch_bounds__(768) void k3s(
    const unsigned long long* __restrict__ adjT,
    const int* __restrict__ rowmax2d, int* __restrict__ out_idx) {
  __shared__ int nxtA[N_PED], nxtB[N_PED];
  __shared__ int valL[N_PED], labL[N_PED], rankL[N_PED];
  const int n = threadIdx.x;

  int cm = -1;
#pragma unroll
  for (int j = 0; j < NW; ++j) {
    int t = rowmax2d[n * NW + j];
    cm = t > cm ? t : cm;
  }
  int v0 = (cm >= 0) ? cm : n;
  valL[n] = v0;

  int succ = n;
  {
    int j = n >> 6, rl = n & 63;
    unsigned long long w0 = (adjT[v0 * NW + j] >> rl) >> 1;
    if (w0) {
      succ = n + __ffsll(w0);
    } else {
      for (++j; j < NW; ++j) {
        unsigned long long ww = adjT[v0 * NW + j];
        if (ww) { succ = j * 64 + __ffsll(ww) - 1; break; }
      }
    }
  }
  nxtA[n] = succ;
  __syncthreads();

  int* src = nxtA;
  int* dst = nxtB;
#pragma unroll
  for (int it = 0; it < 10; ++it) {  // 2^10 >= 767
    dst[n] = src[src[n]];
    __syncthreads();
    int* t = src; src = dst; dst = t;
  }
  labL[n] = valL[src[n]];
  __syncthreads();

  nxtA[n] = 0;  // reuse as flags
  __syncthreads();
  nxtA[labL[n]] = 1;
  __syncthreads();
  if (n < 64) {  // wave 0: 12-segment scan ranks distinct labels ascending
    int f[NW], s = 0;
#pragma unroll
    for (int q = 0; q < NW; ++q) { f[q] = nxtA[n * NW + q]; s += f[q]; }
    int inc = s;
    for (int d = 1; d < 64; d <<= 1) {
      int t = __shfl_up(inc, d);
      if (n >= d) inc += t;
    }
    int run = inc - s;
#pragma unroll
    for (int q = 0; q < NW; ++q) { run += f[q]; rankL[n * NW + q] = run - 1; }
  }
  __syncthreads();
  out_idx[n] = rankL[labL[n]];
}

// K4: group-mean pooling, one wave per (ct, g); shfl_xor tree reduce.
__global__ __launch_bounds__(256) void k4_pool(
    const float* __restrict__ vrel, const int* __restrict__ idx,
    float* __restrict__ pool) {
  int wv = blockIdx.x * 4 + (threadIdx.x >> 6);  // 0..12287
  int lane = threadIdx.x & 63;
  int ct = wv / N_PED;
  int g = wv % N_PED;
  float s = 0.f;
  int cnt = 0;
#pragma unroll
  for (int k = 0; k < NW; ++k) {
    int n = k * 64 + lane;
    int id = idx[n];
    float v = vrel[ct * N_PED + n];
    bool m = (id == g);
    s += m ? v : 0.f;
    cnt += m ? 1 : 0;
  }
#pragma unroll
  for (int d = 1; d < 64; d <<= 1) {
    s += __shfl_xor(s, d);
    cnt += __shfl_xor(cnt, d);
  }
  if (lane == 0) pool[ct * N_PED + g] = s / fmaxf((float)cnt, 1.0f);
}

// K5: out[o,p,n] = (2*baseline(v_rel) + baseline(pool)[..,idx[n]]) / 3
__global__ __launch_bounds__(256) void k5_final(
    const float* __restrict__ vrel, const float* __restrict__ pool,
    const int* __restrict__ idx, const float* __restrict__ wt,
    const float* __restrict__ wc, float* __restrict__ out) {
  int i = blockIdx.x * 256 + threadIdx.x;
  if (i >= 5 * 12 * N_PED) return;
  int n = i % N_PED;
  int t_ = i / N_PED;
  int p = t_ % 12;
  int o = t_ / 12;
  int g = idx[n];
  float v1 = 0.f, v2 = 0.f;
#pragma unroll
  for (int c = 0; c < 2; ++c) {
    float u1 = 0.f, u2 = 0.f;
#pragma unroll
    for (int t = 0; t < 8; ++t) {
      float wtv = wt[t * 12 + p];
      u1 += wtv * vrel[(c * 8 + t) * N_PED + n];
      u2 += wtv * pool[(c * 8 + t) * N_PED + g];
    }
    float wcv = wc[c * 5 + o];
    v1 += wcv * u1;
    v2 += wcv * u2;
  }
  out[i] = (v1 + v2 + v1) / 3.0f;
}

extern "C" void kernel_launch(void* const* d_in, const int* in_sizes, int n_in,
                              void* d_out, int out_size, void* d_ws, size_t ws_size,
                              hipStream_t stream) {
  const float* va   = (const float*)d_in[0];
  const float* vr   = (const float*)d_in[1];
  const float* velw = (const float*)d_in[2];
  const float* velb = (const float*)d_in[3];
  const float* g1w  = (const float*)d_in[4];
  const float* g1b  = (const float*)d_in[5];
  const float* gam  = (const float*)d_in[6];
  const float* bet  = (const float*)d_in[7];
  const float* g2w  = (const float*)d_in[8];
  const float* g2b  = (const float*)d_in[9];
  const float* wt   = (const float*)d_in[10];
  const float* wc   = (const float*)d_in[11];
  float* out = (float*)d_out;

  char* ws = (char*)d_ws;
  double* A = (double*)(ws + 0);
  double* P = (double*)(ws + 98304);
  unsigned long long* adjT = (unsigned long long*)(ws + 98568);
  int* rowmax2d = (int*)(ws + 172296);
  int* idx = (int*)(ws + 209160);
  float* pool = (float*)(ws + 212232);

  k1_prep<<<3, 256, 0, stream>>>(va, vr, velw, velb, g1w, g1b, gam, bet, g2w, g2b, A, P);
  k2f<<<144, 256, 0, stream>>>(A, P, adjT, rowmax2d);
  k3s<<<1, 768, 0, stream>>>(adjT, rowmax2d, idx);
  k4_pool<<<3072, 256, 0, stream>>>(vr, idx, pool);
  k5_final<<<180, 256, 0, stream>>>(vr, pool, idx, wt, wc, out);
}